// Round 7
// baseline (249.178 us; speedup 1.0000x reference)
//
#include <hip/hip_runtime.h>
#include <hip/hip_bf16.h>
#include <math.h>

#define HW 3136
#define NC 192
#define NHEADS 6
#define IMG 56
#define NATT 486
#define NATTP 896          // padded att cols: head*144 + k*16 + l
#define ATT_SCALE 0.17677669529663687f  // 32^-0.5

typedef __attribute__((ext_vector_type(8))) short short8;
typedef __attribute__((ext_vector_type(8))) unsigned short ushort8;
typedef __attribute__((ext_vector_type(4))) float float4v;

__device__ __forceinline__ float bf2f(unsigned short u) {
    unsigned int x = ((unsigned int)u) << 16;
    return __builtin_bit_cast(float, x);
}
__device__ __forceinline__ unsigned short f2bf(float f) {
    __hip_bfloat16 h = __float2bfloat16(f);
    return __builtin_bit_cast(unsigned short, h);
}
__device__ __forceinline__ void gload_lds16(const void* g, void* l) {
    __builtin_amdgcn_global_load_lds((const __attribute__((address_space(1))) void*)g,
                                     (__attribute__((address_space(3))) void*)l, 16, 0, 0);
}

// x [16][192][3136] fp32 -> xt [50176][192] bf16 (channels-last). grid (784,3), block 256.
__global__ __launch_bounds__(256) void transpose_x(const float* __restrict__ x,
                                                   unsigned short* __restrict__ xt)
{
    __shared__ float tile[64][65];
    int bx = blockIdx.x;
    int n = (bx * 64) / HW;
    int hw0 = (bx * 64) % HW;
    int c0 = blockIdx.y * 64;
    int tl = threadIdx.x & 63, tg = threadIdx.x >> 6;
    const float* xn = x + (size_t)n * NC * HW;
#pragma unroll
    for (int i = 0; i < 16; ++i)
        tile[tg * 16 + i][tl] = xn[(size_t)(c0 + tg * 16 + i) * HW + hw0 + tl];
    __syncthreads();
    unsigned short* xp = xt + ((size_t)n * HW + hw0) * NC + c0;
#pragma unroll
    for (int i = 0; i < 16; ++i) {
        int hwr = tg * 16 + i;
        xp[(size_t)hwr * NC + tl] = f2bf(tile[tl][hwr]);
    }
}

// Weight prep: Wv,Wp -> [d][k] bf16; Wa -> permuted+padded [896][192] bf16, ba -> bap[896].
// grid 672, block 256.
__global__ __launch_bounds__(256) void prep_weights(
    const float* __restrict__ Wv, const float* __restrict__ Wa, const float* __restrict__ Wp,
    const float* __restrict__ ba,
    unsigned short* __restrict__ Wvt, unsigned short* __restrict__ Wat,
    unsigned short* __restrict__ Wpt, float* __restrict__ bap)
{
    int idx = blockIdx.x * 256 + threadIdx.x;
    if (idx < 36864) {
        int d = idx / 192, k = idx % 192;
        Wvt[idx] = f2bf(Wv[(size_t)k * NC + d]);
        Wpt[idx] = f2bf(Wp[(size_t)k * NC + d]);
    }
    if (idx < 172032) {                       // 896*192
        int dp = idx / 192, kch = idx % 192;
        int head = dp / 144, r = dp % 144, k = r >> 4, l = r & 15;
        bool valid = (dp < 864) && (l < 9);
        int src = head * 81 + k * 9 + l;
        Wat[idx] = valid ? f2bf(Wa[(size_t)kch * NATT + src]) : (unsigned short)0;
        if (kch == 0) bap[dp] = valid ? ba[src] : 0.f;
    }
}

// Fused GEMM1+GEMM2, A-stationary: block = 64 rows x 1088 cols (192 v + 896 att).
// A staged once in LDS, A-frags in registers; 17 col-tiles, double-buffered B.
__global__ __launch_bounds__(256) void gemm12(
    const unsigned short* __restrict__ A,      // xt [50176][192]
    const unsigned short* __restrict__ Wv192,  // [192][192]
    const unsigned short* __restrict__ Wa896,  // [896][192]
    const float* __restrict__ bap,             // [896]
    unsigned short* __restrict__ vbf,          // [50176][192]
    unsigned short* __restrict__ attb)         // [50176][896]
{
    __shared__ __align__(16) unsigned short As[6 * 64 * 32];
    __shared__ __align__(16) unsigned short Bs[2][6 * 64 * 32];
    int t = threadIdx.x, lane = t & 63, wave = t >> 6;
    int row0 = blockIdx.x * 64;

    // stage A: LDS layout [kk][row][32 shorts]; global row-major [row][192]
    {
        const char* Ab = (const char*)A + (size_t)row0 * 384;
#pragma unroll
        for (int r = 0; r < 6; ++r) {
            int o = (wave * 6 + r) * 1024;           // byte region in As
            int kk = o >> 12;
            int rsub = (o & 4095) >> 6;
            const char* g = Ab + (size_t)(rsub + (lane >> 2)) * 384 + kk * 64 + (lane & 3) * 16;
            gload_lds16(g, (char*)As + o);
        }
    }
    // stage B tile 0
    {
        const char* Bb = (const char*)Wv192;
#pragma unroll
        for (int r = 0; r < 6; ++r) {
            int o = (wave * 6 + r) * 1024;
            int kk = o >> 12;
            int rsub = (o & 4095) >> 6;
            const char* g = Bb + (size_t)(rsub + (lane >> 2)) * 384 + kk * 64 + (lane & 3) * 16;
            gload_lds16(g, (char*)Bs[0] + o);
        }
    }
    __syncthreads();

    int fr = lane & 15, fq = lane >> 4;
    short8 af[6];
#pragma unroll
    for (int kk = 0; kk < 6; ++kk)
        af[kk] = *(const short8*)((const char*)As + kk * 4096 + (wave * 16 + fr) * 64 + fq * 16);

    for (int tile = 0; tile < 17; ++tile) {
        int buf = tile & 1;
        if (tile + 1 < 17) {
            int nt = tile + 1;
            const char* Bb = (nt < 3) ? (const char*)Wv192 + (size_t)nt * 64 * 384
                                      : (const char*)Wa896 + (size_t)(nt - 3) * 64 * 384;
#pragma unroll
            for (int r = 0; r < 6; ++r) {
                int o = (wave * 6 + r) * 1024;
                int kk = o >> 12;
                int rsub = (o & 4095) >> 6;
                const char* g = Bb + (size_t)(rsub + (lane >> 2)) * 384 + kk * 64 + (lane & 3) * 16;
                gload_lds16(g, (char*)Bs[buf ^ 1] + o);
            }
        }
        float4v acc[4] = {};
#pragma unroll
        for (int kk = 0; kk < 6; ++kk) {
#pragma unroll
            for (int ni = 0; ni < 4; ++ni) {
                short8 bf = *(const short8*)((const char*)Bs[buf] + kk * 4096 +
                                             (ni * 16 + fr) * 64 + fq * 16);
                acc[ni] = __builtin_amdgcn_mfma_f32_16x16x32_bf16(af[kk], bf, acc[ni], 0, 0, 0);
            }
        }
        int n0 = tile * 64;
#pragma unroll
        for (int ni = 0; ni < 4; ++ni) {
            int col = n0 + ni * 16 + fr;
            bool isatt = col >= 192;
            float bias = isatt ? bap[col - 192] : 0.f;
#pragma unroll
            for (int r = 0; r < 4; ++r) {
                int row = row0 + wave * 16 + fq * 4 + r;
                float val = acc[ni][r];
                if (!isatt)
                    vbf[(size_t)row * NC + col] = f2bf(val);
                else
                    attb[(size_t)row * NATTP + (col - 192)] = f2bf(val + bias);
            }
        }
        __syncthreads();
    }
}

// GEMM3: C[m][n] = sum_k Wpt[m][k]*fold[n][k]; m = out channel, n = position.
// Stores fp32 channels-first + bias. grid (784, 3), block 256.
__global__ __launch_bounds__(256) void gemm_out(
    const unsigned short* __restrict__ A, const unsigned short* __restrict__ B,
    const float* __restrict__ bias, float* __restrict__ Cout)
{
    __shared__ __align__(16) unsigned short As[64 * 32];
    __shared__ __align__(16) unsigned short Bs[64 * 32];
    int t = threadIdx.x, lane = t & 63, wave = t >> 6;
    int m0 = blockIdx.y * 64, n0 = blockIdx.x * 64;
    int srow = lane >> 2, squad = lane & 3;
    const unsigned short* ga = A + (size_t)(m0 + wave * 16 + srow) * NC + squad * 8;
    const unsigned short* gb = B + (size_t)(n0 + wave * 16 + srow) * NC + squad * 8;
    unsigned short* la = As + wave * 512;
    unsigned short* lb = Bs + wave * 512;
    int fr = lane & 15, fq = lane >> 4;
    int wm = (wave >> 1) * 32, wn = (wave & 1) * 32;
    float4v acc[2][2] = {};

    for (int k0 = 0; k0 < NC; k0 += 32) {
        gload_lds16(ga + k0, la);
        gload_lds16(gb + k0, lb);
        __syncthreads();
        short8 af[2], bfv[2];
#pragma unroll
        for (int mi = 0; mi < 2; ++mi)
            af[mi] = *(const short8*)&As[(wm + mi * 16 + fr) * 32 + fq * 8];
#pragma unroll
        for (int ni = 0; ni < 2; ++ni)
            bfv[ni] = *(const short8*)&Bs[(wn + ni * 16 + fr) * 32 + fq * 8];
#pragma unroll
        for (int mi = 0; mi < 2; ++mi)
#pragma unroll
            for (int ni = 0; ni < 2; ++ni)
                acc[mi][ni] = __builtin_amdgcn_mfma_f32_16x16x32_bf16(
                    af[mi], bfv[ni], acc[mi][ni], 0, 0, 0);
        __syncthreads();
    }
#pragma unroll
    for (int mi = 0; mi < 2; ++mi)
#pragma unroll
        for (int ni = 0; ni < 2; ++ni)
#pragma unroll
            for (int r = 0; r < 4; ++r) {
                int m = m0 + wm + mi * 16 + fq * 4 + r;
                int n = n0 + wn + ni * 16 + fr;
                int img = n / HW, phw = n - img * HW;
                Cout[(size_t)img * (NC * HW) + (size_t)m * HW + phw] =
                    acc[mi][ni][r] + bias[m];
            }
}

// Fused softmax(l) + fold/unfold weight-combine (25-tap) + aggregation.
// Thread = (group, quarter): 8 channels. Group id G = (n*HW+hw)*6 + head
// (head fastest) so 24 consecutive lanes cover all 192 channels of one
// position -> contiguous v loads / fold stores. Softmax duplicated in lane
// quads (same att addresses -> broadcast). att [rem][896], v/fold [rem][192].
__global__ __launch_bounds__(256) void fused_att_agg(
    const unsigned short* __restrict__ att, const unsigned short* __restrict__ v,
    unsigned short* __restrict__ fold)
{
    int t = threadIdx.x;
    int G = blockIdx.x * 64 + (t >> 2);    // (n*HW+hw)*6 + head
    int q8 = t & 3;                        // channel quarter
    int head = G % NHEADS;
    int rem = G / NHEADS;                  // n*HW + hw
    int hw = rem % HW;
    int h = hw / IMG, w = hw % IMG;

    const unsigned short* attn = att + (size_t)rem * NATTP + head * 144;
    float wc[25];
#pragma unroll
    for (int d = 0; d < 25; ++d) wc[d] = 0.f;
#pragma unroll
    for (int k = 0; k < 9; ++k) {
        const int oky = k / 3 - 1, okx = k % 3 - 1;
        int hh = h - oky, ww = w - okx;
        if (hh < 0 || hh >= IMG || ww < 0 || ww >= IMG) continue;
        const unsigned short* ap = attn - (ptrdiff_t)(oky * IMG + okx) * NATTP + k * 16;
        ushort8 a8 = *(const ushort8*)ap;       // 16-B aligned
        float a[9];
#pragma unroll
        for (int l = 0; l < 8; ++l) a[l] = bf2f(a8[l]);
        a[8] = bf2f(ap[8]);
        float m = -1e30f;
#pragma unroll
        for (int l = 0; l < 9; ++l) m = fmaxf(m, a[l]);
        float s = 0.f;
#pragma unroll
        for (int l = 0; l < 9; ++l) {
            a[l] = __expf((a[l] - m) * ATT_SCALE);
            s += a[l];
        }
        float r = 1.f / s;
#pragma unroll
        for (int l = 0; l < 9; ++l) {
            const int dy = (l / 3 - 1) - oky + 2;
            const int dx = (l % 3 - 1) - okx + 2;
            wc[dy * 5 + dx] += a[l] * r;
        }
    }

    const unsigned short* vb = v + (size_t)rem * NC + head * 32 + q8 * 8;
    float acc[8];
#pragma unroll
    for (int i = 0; i < 8; ++i) acc[i] = 0.f;
#pragma unroll
    for (int d = 0; d < 25; ++d) {
        const int dy = d / 5 - 2, dx = d % 5 - 2;
        int hh = h + dy, ww = w + dx;
        bool ok = (hh >= 0) & (hh < IMG) & (ww >= 0) & (ww < IMG);
        float wf = ok ? wc[d] : 0.f;
        const unsigned short* vp = vb + (ok ? (dy * IMG + dx) * NC : 0);
        ushort8 vv = *(const ushort8*)vp;
#pragma unroll
        for (int i = 0; i < 8; ++i)
            acc[i] += wf * bf2f(vv[i]);
    }
    unsigned short* fo = fold + (size_t)rem * NC + head * 32 + q8 * 8;
    ushort8 ov;
#pragma unroll
    for (int i = 0; i < 8; ++i) ov[i] = f2bf(acc[i]);
    *(ushort8*)fo = ov;
}

extern "C" void kernel_launch(void* const* d_in, const int* in_sizes, int n_in,
                              void* d_out, int out_size, void* d_ws, size_t ws_size,
                              hipStream_t stream)
{
    const float* x  = (const float*)d_in[0];
    const float* Wv = (const float*)d_in[1];
    const float* Wa = (const float*)d_in[2];
    const float* ba = (const float*)d_in[3];
    const float* Wp = (const float*)d_in[4];
    const float* bp = (const float*)d_in[5];
    float* out = (float*)d_out;

    unsigned short* xt    = (unsigned short*)d_ws;       // 50176*192
    unsigned short* vbf   = xt + 9633792;                // 50176*192
    unsigned short* attb  = vbf + 9633792;               // 50176*896
    unsigned short* foldb = attb + 44957696;             // 50176*192
    unsigned short* wvt   = foldb + 9633792;             // 192*192
    unsigned short* wat   = wvt + 36864;                 // 896*192
    unsigned short* wpt   = wat + 172032;                // 192*192
    float*          bap   = (float*)(wpt + 36864);       // 896 floats

    dim3 blk(256);
    prep_weights<<<672, blk, 0, stream>>>(Wv, Wa, Wp, ba, wvt, wat, wpt, bap);
    transpose_x<<<dim3(784, 3), blk, 0, stream>>>(x, xt);
    gemm12<<<784, blk, 0, stream>>>(xt, wvt, wat, bap, vbf, attb);
    fused_att_agg<<<4704, blk, 0, stream>>>(attb, vbf, foldb);
    gemm_out<<<dim3(784, 3), blk, 0, stream>>>(wpt, foldb, bp, out);
}

// Round 8
// 219.923 us; speedup vs baseline: 1.1330x; 1.1330x over previous
//
#include <hip/hip_runtime.h>
#include <hip/hip_bf16.h>
#include <math.h>

#define HW 3136
#define NC 192
#define NHEADS 6
#define IMG 56
#define NATT 486
#define NATTP 896          // padded att cols: head*144 + k*16 + l
#define ATT_SCALE 0.17677669529663687f  // 32^-0.5

typedef __attribute__((ext_vector_type(8))) short short8;
typedef __attribute__((ext_vector_type(8))) unsigned short ushort8;
typedef __attribute__((ext_vector_type(4))) float float4v;

__device__ __forceinline__ float bf2f(unsigned short u) {
    unsigned int x = ((unsigned int)u) << 16;
    return __builtin_bit_cast(float, x);
}
__device__ __forceinline__ unsigned short f2bf(float f) {
    __hip_bfloat16 h = __float2bfloat16(f);
    return __builtin_bit_cast(unsigned short, h);
}
__device__ __forceinline__ void gload_lds16(const void* g, void* l) {
    __builtin_amdgcn_global_load_lds((const __attribute__((address_space(1))) void*)g,
                                     (__attribute__((address_space(3))) void*)l, 16, 0, 0);
}

// x [16][192][3136] fp32 -> xt [50176][192] bf16 (channels-last). grid (784,3), block 256.
__global__ __launch_bounds__(256) void transpose_x(const float* __restrict__ x,
                                                   unsigned short* __restrict__ xt)
{
    __shared__ float tile[64][65];
    int bx = blockIdx.x;
    int n = (bx * 64) / HW;
    int hw0 = (bx * 64) % HW;
    int c0 = blockIdx.y * 64;
    int tl = threadIdx.x & 63, tg = threadIdx.x >> 6;
    const float* xn = x + (size_t)n * NC * HW;
#pragma unroll
    for (int i = 0; i < 16; ++i)
        tile[tg * 16 + i][tl] = xn[(size_t)(c0 + tg * 16 + i) * HW + hw0 + tl];
    __syncthreads();
    unsigned short* xp = xt + ((size_t)n * HW + hw0) * NC + c0;
#pragma unroll
    for (int i = 0; i < 16; ++i) {
        int hwr = tg * 16 + i;
        xp[(size_t)hwr * NC + tl] = f2bf(tile[tl][hwr]);
    }
}

// Weight prep: Wv,Wp -> [d][k] bf16; Wa -> permuted+padded [896][192] bf16, ba -> bap[896].
// grid 672, block 256.
__global__ __launch_bounds__(256) void prep_weights(
    const float* __restrict__ Wv, const float* __restrict__ Wa, const float* __restrict__ Wp,
    const float* __restrict__ ba,
    unsigned short* __restrict__ Wvt, unsigned short* __restrict__ Wat,
    unsigned short* __restrict__ Wpt, float* __restrict__ bap)
{
    int idx = blockIdx.x * 256 + threadIdx.x;
    if (idx < 36864) {
        int d = idx / 192, k = idx % 192;
        Wvt[idx] = f2bf(Wv[(size_t)k * NC + d]);
        Wpt[idx] = f2bf(Wp[(size_t)k * NC + d]);
    }
    if (idx < 172032) {                       // 896*192
        int dp = idx / 192, kch = idx % 192;
        int head = dp / 144, r = dp % 144, k = r >> 4, l = r & 15;
        bool valid = (dp < 864) && (l < 9);
        int src = head * 81 + k * 9 + l;
        Wat[idx] = valid ? f2bf(Wa[(size_t)kch * NATT + src]) : (unsigned short)0;
        if (kch == 0) bap[dp] = valid ? ba[src] : 0.f;
    }
}

// Fused GEMM1+GEMM2, A-stationary: block = 64 rows x 1088 cols (192 v + 896 att).
// A staged once in LDS, A-frags in registers; 17 col-tiles, double-buffered B.
__global__ __launch_bounds__(256) void gemm12(
    const unsigned short* __restrict__ A,      // xt [50176][192]
    const unsigned short* __restrict__ Wv192,  // [192][192]
    const unsigned short* __restrict__ Wa896,  // [896][192]
    const float* __restrict__ bap,             // [896]
    unsigned short* __restrict__ vbf,          // [50176][192]
    unsigned short* __restrict__ attb)         // [50176][896]
{
    __shared__ __align__(16) unsigned short As[6 * 64 * 32];
    __shared__ __align__(16) unsigned short Bs[2][6 * 64 * 32];
    int t = threadIdx.x, lane = t & 63, wave = t >> 6;
    int row0 = blockIdx.x * 64;

    // stage A: LDS layout [kk][row][32 shorts]; global row-major [row][192]
    {
        const char* Ab = (const char*)A + (size_t)row0 * 384;
#pragma unroll
        for (int r = 0; r < 6; ++r) {
            int o = (wave * 6 + r) * 1024;           // byte region in As
            int kk = o >> 12;
            int rsub = (o & 4095) >> 6;
            const char* g = Ab + (size_t)(rsub + (lane >> 2)) * 384 + kk * 64 + (lane & 3) * 16;
            gload_lds16(g, (char*)As + o);
        }
    }
    // stage B tile 0
    {
        const char* Bb = (const char*)Wv192;
#pragma unroll
        for (int r = 0; r < 6; ++r) {
            int o = (wave * 6 + r) * 1024;
            int kk = o >> 12;
            int rsub = (o & 4095) >> 6;
            const char* g = Bb + (size_t)(rsub + (lane >> 2)) * 384 + kk * 64 + (lane & 3) * 16;
            gload_lds16(g, (char*)Bs[0] + o);
        }
    }
    __syncthreads();

    int fr = lane & 15, fq = lane >> 4;
    short8 af[6];
#pragma unroll
    for (int kk = 0; kk < 6; ++kk)
        af[kk] = *(const short8*)((const char*)As + kk * 4096 + (wave * 16 + fr) * 64 + fq * 16);

    for (int tile = 0; tile < 17; ++tile) {
        int buf = tile & 1;
        if (tile + 1 < 17) {
            int nt = tile + 1;
            const char* Bb = (nt < 3) ? (const char*)Wv192 + (size_t)nt * 64 * 384
                                      : (const char*)Wa896 + (size_t)(nt - 3) * 64 * 384;
#pragma unroll
            for (int r = 0; r < 6; ++r) {
                int o = (wave * 6 + r) * 1024;
                int kk = o >> 12;
                int rsub = (o & 4095) >> 6;
                const char* g = Bb + (size_t)(rsub + (lane >> 2)) * 384 + kk * 64 + (lane & 3) * 16;
                gload_lds16(g, (char*)Bs[buf ^ 1] + o);
            }
        }
        float4v acc[4] = {};
#pragma unroll
        for (int kk = 0; kk < 6; ++kk) {
#pragma unroll
            for (int ni = 0; ni < 4; ++ni) {
                short8 bf = *(const short8*)((const char*)Bs[buf] + kk * 4096 +
                                             (ni * 16 + fr) * 64 + fq * 16);
                acc[ni] = __builtin_amdgcn_mfma_f32_16x16x32_bf16(af[kk], bf, acc[ni], 0, 0, 0);
            }
        }
        int n0 = tile * 64;
#pragma unroll
        for (int ni = 0; ni < 4; ++ni) {
            int col = n0 + ni * 16 + fr;
            bool isatt = col >= 192;
            float bias = isatt ? bap[col - 192] : 0.f;
#pragma unroll
            for (int r = 0; r < 4; ++r) {
                int row = row0 + wave * 16 + fq * 4 + r;
                float val = acc[ni][r];
                if (!isatt)
                    vbf[(size_t)row * NC + col] = f2bf(val);
                else
                    attb[(size_t)row * NATTP + (col - 192)] = f2bf(val + bias);
            }
        }
        __syncthreads();
    }
}

// GEMM3: C[m][n] = sum_k Wpt[m][k]*fold[n][k]; m = out channel, n = position.
// Stores fp32 channels-first + bias. grid (784, 3), block 256.
__global__ __launch_bounds__(256) void gemm_out(
    const unsigned short* __restrict__ A, const unsigned short* __restrict__ B,
    const float* __restrict__ bias, float* __restrict__ Cout)
{
    __shared__ __align__(16) unsigned short As[64 * 32];
    __shared__ __align__(16) unsigned short Bs[64 * 32];
    int t = threadIdx.x, lane = t & 63, wave = t >> 6;
    int m0 = blockIdx.y * 64, n0 = blockIdx.x * 64;
    int srow = lane >> 2, squad = lane & 3;
    const unsigned short* ga = A + (size_t)(m0 + wave * 16 + srow) * NC + squad * 8;
    const unsigned short* gb = B + (size_t)(n0 + wave * 16 + srow) * NC + squad * 8;
    unsigned short* la = As + wave * 512;
    unsigned short* lb = Bs + wave * 512;
    int fr = lane & 15, fq = lane >> 4;
    int wm = (wave >> 1) * 32, wn = (wave & 1) * 32;
    float4v acc[2][2] = {};

    for (int k0 = 0; k0 < NC; k0 += 32) {
        gload_lds16(ga + k0, la);
        gload_lds16(gb + k0, lb);
        __syncthreads();
        short8 af[2], bfv[2];
#pragma unroll
        for (int mi = 0; mi < 2; ++mi)
            af[mi] = *(const short8*)&As[(wm + mi * 16 + fr) * 32 + fq * 8];
#pragma unroll
        for (int ni = 0; ni < 2; ++ni)
            bfv[ni] = *(const short8*)&Bs[(wn + ni * 16 + fr) * 32 + fq * 8];
#pragma unroll
        for (int mi = 0; mi < 2; ++mi)
#pragma unroll
            for (int ni = 0; ni < 2; ++ni)
                acc[mi][ni] = __builtin_amdgcn_mfma_f32_16x16x32_bf16(
                    af[mi], bfv[ni], acc[mi][ni], 0, 0, 0);
        __syncthreads();
    }
#pragma unroll
    for (int mi = 0; mi < 2; ++mi)
#pragma unroll
        for (int ni = 0; ni < 2; ++ni)
#pragma unroll
            for (int r = 0; r < 4; ++r) {
                int m = m0 + wm + mi * 16 + fq * 4 + r;
                int n = n0 + wn + ni * 16 + fr;
                int img = n / HW, phw = n - img * HW;
                Cout[(size_t)img * (NC * HW) + (size_t)m * HW + phw] =
                    acc[mi][ni][r] + bias[m];
            }
}

// Fused softmax + weight-combine + aggregation, v3 (LDS-shared stencil weights).
// Block = 32 positions x 6 heads = 192 groups.
// Phase 1: threads 0..191 (waves 0-2) compute full softmax for one group each
//   (att locality preserved) -> wc[25] f32 to LDS (stride 25, coprime w/ 32 banks).
// Phase 2: 768 items = (pos, head, quarter), 3 per thread; 24 consecutive lanes
//   cover one full 384-B position row of v -> coalesced; wc read from LDS
//   (quad lanes broadcast). Interior fast path drops bounds VALU.
__global__ __launch_bounds__(256) void fused_att_agg(
    const unsigned short* __restrict__ att, const unsigned short* __restrict__ v,
    unsigned short* __restrict__ fold)
{
    __shared__ float swc[192 * 25];
    int t = threadIdx.x;
    int pos_base = blockIdx.x * 32;

    if (t < 192) {
        int pos = t / 6, head = t - pos * 6;
        int rem = pos_base + pos;
        int hw = rem % HW;
        int h = hw / IMG, w = hw % IMG;
        const unsigned short* attn = att + (size_t)rem * NATTP + head * 144;
        float wc[25];
#pragma unroll
        for (int d = 0; d < 25; ++d) wc[d] = 0.f;
#pragma unroll
        for (int k = 0; k < 9; ++k) {
            const int oky = k / 3 - 1, okx = k % 3 - 1;
            int hh = h - oky, ww = w - okx;
            if (hh < 0 || hh >= IMG || ww < 0 || ww >= IMG) continue;
            const unsigned short* ap = attn - (ptrdiff_t)(oky * IMG + okx) * NATTP + k * 16;
            ushort8 a8 = *(const ushort8*)ap;       // 16-B aligned
            float a[9];
#pragma unroll
            for (int l = 0; l < 8; ++l) a[l] = bf2f(a8[l]);
            a[8] = bf2f(ap[8]);
            float m = -1e30f;
#pragma unroll
            for (int l = 0; l < 9; ++l) m = fmaxf(m, a[l]);
            float s = 0.f;
#pragma unroll
            for (int l = 0; l < 9; ++l) {
                a[l] = __expf((a[l] - m) * ATT_SCALE);
                s += a[l];
            }
            float r = 1.f / s;
#pragma unroll
            for (int l = 0; l < 9; ++l) {
                const int dy = (l / 3 - 1) - oky + 2;
                const int dx = (l % 3 - 1) - okx + 2;
                wc[dy * 5 + dx] += a[l] * r;
            }
        }
        float* o = swc + t * 25;
#pragma unroll
        for (int d = 0; d < 25; ++d) o[d] = wc[d];
    }
    __syncthreads();

#pragma unroll
    for (int i = 0; i < 3; ++i) {
        int item = i * 256 + t;                 // 0..767
        int pos = item / 24, sub = item - pos * 24;
        int head = sub >> 2, q8 = sub & 3;
        int rem = pos_base + pos;
        int hw = rem % HW;
        int h = hw / IMG, w = hw % IMG;
        const float* wp = swc + (pos * 6 + head) * 25;
        const unsigned short* vb = v + (size_t)rem * NC + head * 32 + q8 * 8;
        float acc[8];
#pragma unroll
        for (int j = 0; j < 8; ++j) acc[j] = 0.f;
        if (h >= 2 && h < IMG - 2 && w >= 2 && w < IMG - 2) {
#pragma unroll
            for (int d = 0; d < 25; ++d) {
                const int dy = d / 5 - 2, dx = d % 5 - 2;
                float wf = wp[d];
                ushort8 vv = *(const ushort8*)(vb + (dy * IMG + dx) * NC);
#pragma unroll
                for (int j = 0; j < 8; ++j)
                    acc[j] += wf * bf2f(vv[j]);
            }
        } else {
#pragma unroll
            for (int d = 0; d < 25; ++d) {
                const int dy = d / 5 - 2, dx = d % 5 - 2;
                int hh = h + dy, ww = w + dx;
                bool ok = (hh >= 0) & (hh < IMG) & (ww >= 0) & (ww < IMG);
                float wf = ok ? wp[d] : 0.f;
                const unsigned short* vp = vb + (ok ? (dy * IMG + dx) * NC : 0);
                ushort8 vv = *(const ushort8*)vp;
#pragma unroll
                for (int j = 0; j < 8; ++j)
                    acc[j] += wf * bf2f(vv[j]);
            }
        }
        unsigned short* fo = fold + (size_t)rem * NC + head * 32 + q8 * 8;
        ushort8 ov;
#pragma unroll
        for (int j = 0; j < 8; ++j) ov[j] = f2bf(acc[j]);
        *(ushort8*)fo = ov;
    }
}

extern "C" void kernel_launch(void* const* d_in, const int* in_sizes, int n_in,
                              void* d_out, int out_size, void* d_ws, size_t ws_size,
                              hipStream_t stream)
{
    const float* x  = (const float*)d_in[0];
    const float* Wv = (const float*)d_in[1];
    const float* Wa = (const float*)d_in[2];
    const float* ba = (const float*)d_in[3];
    const float* Wp = (const float*)d_in[4];
    const float* bp = (const float*)d_in[5];
    float* out = (float*)d_out;

    unsigned short* xt    = (unsigned short*)d_ws;       // 50176*192
    unsigned short* vbf   = xt + 9633792;                // 50176*192
    unsigned short* attb  = vbf + 9633792;               // 50176*896
    unsigned short* foldb = attb + 44957696;             // 50176*192
    unsigned short* wvt   = foldb + 9633792;             // 192*192
    unsigned short* wat   = wvt + 36864;                 // 896*192
    unsigned short* wpt   = wat + 172032;                // 192*192
    float*          bap   = (float*)(wpt + 36864);       // 896 floats

    dim3 blk(256);
    prep_weights<<<672, blk, 0, stream>>>(Wv, Wa, Wp, ba, wvt, wat, wpt, bap);
    transpose_x<<<dim3(784, 3), blk, 0, stream>>>(x, xt);
    gemm12<<<784, blk, 0, stream>>>(xt, wvt, wat, bap, vbf, attb);
    fused_att_agg<<<1568, blk, 0, stream>>>(attb, vbf, foldb);
    gemm_out<<<dim3(784, 3), blk, 0, stream>>>(wpt, foldb, bp, out);
}